// Round 9
// baseline (221.228 us; speedup 1.0000x reference)
//
#include <hip/hip_runtime.h>
#include <hip/hip_bf16.h>
#include <math.h>

#define D_MODEL   256
#define D_STATE   64
#define D_CONV    4
#define D_INNER   512
#define HEADDIM   64
#define NHEADS    8
#define CONV_DIM  640     // D_INNER + 2*D_STATE
#define D_IN_PROJ 1160    // 2*D_INNER + 2*D_STATE + NHEADS
#define ZXP       1280    // padded in_proj N (10 x 128 tiles)
#define SEQLEN    1024
#define BATCH     8
#define NROWS     8192    // BATCH * SEQLEN
#define EPS       1e-5f
#define CHUNK     64
#define NCHUNK    (SEQLEN / CHUNK)   // 16

typedef __attribute__((ext_vector_type(8))) short bf16x8;
typedef __attribute__((ext_vector_type(4))) short s16x4;
typedef __attribute__((ext_vector_type(8))) unsigned short u16x8;
typedef __attribute__((ext_vector_type(4))) unsigned short u16x4;
typedef __attribute__((ext_vector_type(4))) float f32x4;
typedef unsigned int u32;
typedef unsigned short u16;

__device__ __forceinline__ void cp16(const short* g, short* l) {
    __builtin_amdgcn_global_load_lds((const __attribute__((address_space(1))) u32*)g,
                                     (__attribute__((address_space(3))) u32*)l, 16, 0, 0);
}
__device__ __forceinline__ u16 bfc(float f) {
    union { __hip_bfloat16 h; u16 u; } cv;
    cv.h = __float2bfloat16(f);
    return cv.u;
}
__device__ __forceinline__ float bf2f(u16 u) {
    union { u32 v; float f; } cv;
    cv.v = ((u32)u) << 16;
    return cv.f;
}
__device__ __forceinline__ void store_out(float* p, float v) { *p = v; }
__device__ __forceinline__ void store_out(__hip_bfloat16* p, float v) { *p = __float2bfloat16(v); }

// 64-col bf16 LDS tile, XOR-octet swizzle
__device__ __forceinline__ int swz(int row, int col) {
    return row * 64 + (((col & 56) ^ ((row & 7) << 3)) | (col & 7));
}
__device__ __forceinline__ bf16x8 ldfrag(const short* base, int row, int oct) {
    return *(const bf16x8*)&base[row * 64 + ((oct * 8) ^ ((row & 7) * 8))];
}
__device__ __forceinline__ void wr2u(short* base, int row, int col2, u16 a, u16 b) {
    int idx = row * 64 + (((col2 & 56) ^ ((row & 7) << 3)) | (col2 & 6));
    *(u32*)&base[idx] = (u32)a | ((u32)b << 16);
}

// ---------------------------------------------------------------------------
// C[m,n] = A[m,:] . W[n,:]  (bf16, fp32 acc). Tile 128x128, BK=32, 4 waves.
// WITH_DT: spill raw cols [D_IN_PROJ-8, D_IN_PROJ) to fp32 dtout.
// ---------------------------------------------------------------------------
template <typename OUT, bool WITH_DT>
__global__ __launch_bounds__(256) void gemm_mfma(const short* __restrict__ A,
                                                 const short* __restrict__ W,
                                                 OUT* __restrict__ C,
                                                 float* __restrict__ dtout,
                                                 int N, int K, int lda) {
    __shared__ short As[128 * 32];
    __shared__ short Ws[128 * 32];
    const int tid  = threadIdx.x;
    const int m0   = blockIdx.y * 128;
    const int n0   = blockIdx.x * 128;
    const int wave = tid >> 6;
    const int lane = tid & 63;
    const int wm   = (wave & 1) * 64;
    const int wn   = (wave >> 1) * 64;
    const int lm   = lane & 15;
    const int lq   = lane >> 4;

    const int sr = tid >> 2;
    const int sk = (tid & 3) * 8;
    const short* ga = A + (size_t)(m0 + sr) * lda + sk;
    const short* gw = W + (size_t)(n0 + sr) * K + sk;
    short* la = &As[tid * 8];
    short* lw = &Ws[tid * 8];
    const size_t ga2 = (size_t)64 * lda;
    const size_t gw2 = (size_t)64 * K;

    f32x4 acc[4][4] = {};

    for (int k0 = 0; k0 < K; k0 += 32) {
        cp16(ga,       la);
        cp16(ga + ga2, la + 64 * 32);
        cp16(gw,       lw);
        cp16(gw + gw2, lw + 64 * 32);
        ga += 32; gw += 32;
        __syncthreads();
        bf16x8 af[4], bfr[4];
        #pragma unroll
        for (int i = 0; i < 4; i++) {
            af[i]  = *(const bf16x8*)&As[(wm + i * 16 + lm) * 32 + lq * 8];
            bfr[i] = *(const bf16x8*)&Ws[(wn + i * 16 + lm) * 32 + lq * 8];
        }
        #pragma unroll
        for (int i = 0; i < 4; i++)
            #pragma unroll
            for (int j = 0; j < 4; j++)
                acc[i][j] = __builtin_amdgcn_mfma_f32_16x16x32_bf16(af[i], bfr[j], acc[i][j], 0, 0, 0);
        __syncthreads();
    }
    #pragma unroll
    for (int i = 0; i < 4; i++)
        #pragma unroll
        for (int r = 0; r < 4; r++) {
            int m = m0 + wm + i * 16 + lq * 4 + r;
            #pragma unroll
            for (int j = 0; j < 4; j++) {
                int n = n0 + wn + j * 16 + lm;
                float v = acc[i][j][r];
                store_out(&C[(size_t)m * N + n], v);
                if (WITH_DT) {
                    if (n >= D_IN_PROJ - NHEADS && n < D_IN_PROJ)
                        dtout[(size_t)m * NHEADS + (n - (D_IN_PROJ - NHEADS))] = v;
                }
            }
        }
}

// ---------------------------------------------------------------------------
// Out-proj GEMM: tile 64(M) x 128(N), BK=32, 4 waves (each 64x32).
// Grid (N/128, M/64) = (2, 128) -> 256 blocks (all CUs).
// SCALE: row m multiplied by rsqrt(sc[m]/512+eps) (RMSNorm epilogue).
// ---------------------------------------------------------------------------
template <typename OUT>
__global__ __launch_bounds__(256) void gemm_out(const short* __restrict__ A,
                                                const short* __restrict__ W,
                                                OUT* __restrict__ C,
                                                const float* __restrict__ sc,
                                                int N, int K) {
    __shared__ short As[64 * 32];
    __shared__ short Ws[128 * 32];
    const int tid  = threadIdx.x;
    const int m0   = blockIdx.y * 64;
    const int n0   = blockIdx.x * 128;
    const int wave = tid >> 6;
    const int lane = tid & 63;
    const int wn   = wave * 32;
    const int lm   = lane & 15;
    const int lq   = lane >> 4;

    const int sr = tid >> 2;          // 0..63
    const int sk = (tid & 3) * 8;
    const short* ga = A + (size_t)(m0 + sr) * K + sk;
    const short* gw = W + (size_t)(n0 + sr) * K + sk;
    short* la = &As[tid * 8];
    short* lw = &Ws[tid * 8];
    const size_t gw2 = (size_t)64 * K;

    f32x4 acc[4][2] = {};

    for (int k0 = 0; k0 < K; k0 += 32) {
        cp16(ga,       la);
        cp16(gw,       lw);
        cp16(gw + gw2, lw + 64 * 32);
        ga += 32; gw += 32;
        __syncthreads();
        bf16x8 af[4], bfr[2];
        #pragma unroll
        for (int i = 0; i < 4; i++)
            af[i] = *(const bf16x8*)&As[(i * 16 + lm) * 32 + lq * 8];
        #pragma unroll
        for (int j = 0; j < 2; j++)
            bfr[j] = *(const bf16x8*)&Ws[(wn + j * 16 + lm) * 32 + lq * 8];
        #pragma unroll
        for (int i = 0; i < 4; i++)
            #pragma unroll
            for (int j = 0; j < 2; j++)
                acc[i][j] = __builtin_amdgcn_mfma_f32_16x16x32_bf16(af[i], bfr[j], acc[i][j], 0, 0, 0);
        __syncthreads();
    }
    #pragma unroll
    for (int i = 0; i < 4; i++)
        #pragma unroll
        for (int r = 0; r < 4; r++) {
            int m = m0 + i * 16 + lq * 4 + r;
            float scl = rsqrtf(sc[m] * (1.f / (float)D_INNER) + EPS);
            #pragma unroll
            for (int j = 0; j < 2; j++) {
                int n = n0 + wn + j * 16 + lm;
                store_out(&C[(size_t)m * N + n], acc[i][j][r] * scl);
            }
        }
}

// ---------------------------------------------------------------------------
// Fused casts: x -> bf16, in_proj_w -> padded bf16, out_proj_w -> bf16.
// ---------------------------------------------------------------------------
#define NX_C  (NROWS * D_MODEL)
#define NWI_C (2 * ZXP * D_MODEL)
#define NWO_C (2 * D_MODEL * D_INNER)
__global__ __launch_bounds__(256) void cast_all_kernel(
    const float* __restrict__ x, const float* __restrict__ wi,
    const float* __restrict__ wo,
    u16* __restrict__ xb, u16* __restrict__ wib, u16* __restrict__ wob)
{
    int idx = blockIdx.x * 256 + threadIdx.x;
    if (idx < NX_C) { xb[idx] = bfc(x[idx]); return; }
    idx -= NX_C;
    if (idx < NWI_C) {
        int k = idx & 255;
        int rb = idx >> 8;
        int r = rb % ZXP;
        int blk = rb / ZXP;
        float v = (r < D_IN_PROJ)
            ? wi[(size_t)blk * D_IN_PROJ * D_MODEL + (size_t)r * D_MODEL + k] : 0.f;
        wib[idx] = bfc(v);
        return;
    }
    idx -= NWI_C;
    wob[idx] = bfc(wo[idx]);
}

// ---------------------------------------------------------------------------
// Depthwise causal conv (width 4) + bias + SiLU; 4 rows x 4 channels / thread.
// ---------------------------------------------------------------------------
__global__ __launch_bounds__(256) void conv_silu_kernel(const u16* __restrict__ zx,
                                                        const float* __restrict__ cw,
                                                        const float* __restrict__ cb,
                                                        u16* __restrict__ out) {
    int idx = blockIdx.x * 256 + threadIdx.x;   // (NROWS/4) * 160
    int c4  = (idx % 160) * 4;
    int r4  = (idx / 160) * 4;
    int l4  = r4 & (SEQLEN - 1);
    float wt[4][4];     // [k][tap]
    #pragma unroll
    for (int k = 0; k < 4; k++)
        *(float4*)&wt[k][0] = *(const float4*)&cw[(c4 + k) * 4];
    float4 cbv = *(const float4*)&cb[c4];
    float cbk[4] = {cbv.x, cbv.y, cbv.z, cbv.w};

    const u16* base = zx + (size_t)r4 * ZXP + D_INNER + c4;
    u16x4 hrow[7];
    #pragma unroll
    for (int k = 0; k < 3; k++) {
        if (l4 != 0) hrow[k] = *(const u16x4*)&base[(k - 3) * ZXP];
        else { hrow[k][0] = 0; hrow[k][1] = 0; hrow[k][2] = 0; hrow[k][3] = 0; }
    }
    #pragma unroll
    for (int k = 3; k < 7; k++)
        hrow[k] = *(const u16x4*)&base[(k - 3) * ZXP];

    #pragma unroll
    for (int rr = 0; rr < 4; rr++) {
        u16x4 o;
        #pragma unroll
        for (int k = 0; k < 4; k++) {
            float acc = cbk[k];
            #pragma unroll
            for (int tap = 0; tap < 4; tap++)
                acc = fmaf(bf2f(hrow[rr + tap][k]), wt[k][tap], acc);
            float s = acc / (1.f + expf(-acc));
            o[k] = bfc(s);
        }
        *(u16x4*)&out[(size_t)(r4 + rr) * CONV_DIM + c4] = o;
    }
}

// ---------------------------------------------------------------------------
// SSD intra-chunk, MFMA. One block per (b, chunk, head), 4 waves.
// Outputs: y_intra (bf16), Schunk (bf16 [n][p]), adec (fp32).
// ---------------------------------------------------------------------------
__global__ __launch_bounds__(256) void ssd_intra_kernel(
    const u16* __restrict__ xc, const float* __restrict__ dtbuf,
    const float* __restrict__ dt_bias, const float* __restrict__ A_log,
    u16* __restrict__ ys, u16* __restrict__ Schunk,
    float* __restrict__ adec, float* __restrict__ ssum)
{
    const int h   = blockIdx.x & 7;
    const int c   = (blockIdx.x >> 3) & 15;
    const int b   = blockIdx.x >> 7;
    const int tid = threadIdx.x;
    const int row0 = b * SEQLEN + c * CHUNK;

    if (tid < 8) ssum[blockIdx.x * 8 + tid] = 0.f;

    __shared__ short Xt[64 * 64];    // [p][t]
    __shared__ short Bn[64 * 64];    // [t][n]
    __shared__ short Cn[64 * 64];    // [t][n]  -> reused as MT [t][tau]
    __shared__ short BTw[64 * 64];   // [n][t], w-folded
    __shared__ float cums[64], dts_s[64], ws_s[64];

    if (tid < 64) {
        const float A = -expf(A_log[h]);
        float raw = dtbuf[(size_t)(row0 + tid) * NHEADS + h] + dt_bias[h];
        float dtv = (raw > 20.f) ? raw : log1pf(expf(raw));
        float v = dtv * A;
        #pragma unroll
        for (int off = 1; off < 64; off <<= 1) {
            float o = __shfl_up(v, off, 64);
            if (tid >= off) v += o;
        }
        float tot = __shfl(v, 63, 64);
        cums[tid]  = v;
        dts_s[tid] = dtv;
        ws_s[tid]  = expf(tot - v) * dtv;
        adec[(size_t)(b * NHEADS + h) * SEQLEN + c * CHUNK + tid] = expf(v);
    }
    __syncthreads();

    {
        const int t2 = (tid >> 3) * 2;
        const int c8 = (tid & 7) * 8;
        const u16* r0 = xc + (size_t)(row0 + t2) * CONV_DIM;
        const u16* r1 = r0 + CONV_DIM;
        u16x8 xv0 = *(const u16x8*)&r0[h * HEADDIM + c8];
        u16x8 xv1 = *(const u16x8*)&r1[h * HEADDIM + c8];
        u16x8 bv0 = *(const u16x8*)&r0[D_INNER + c8];
        u16x8 bv1 = *(const u16x8*)&r1[D_INNER + c8];
        u16x8 cv0 = *(const u16x8*)&r0[D_INNER + D_STATE + c8];
        u16x8 cv1 = *(const u16x8*)&r1[D_INNER + D_STATE + c8];
        *(u16x8*)&Bn[swz(t2,     c8)] = bv0;
        *(u16x8*)&Bn[swz(t2 + 1, c8)] = bv1;
        *(u16x8*)&Cn[swz(t2,     c8)] = cv0;
        *(u16x8*)&Cn[swz(t2 + 1, c8)] = cv1;
        float w0 = ws_s[t2], w1 = ws_s[t2 + 1];
        #pragma unroll
        for (int k = 0; k < 8; k++) {
            wr2u(Xt,  c8 + k, t2, xv0[k], xv1[k]);
            wr2u(BTw, c8 + k, t2, bfc(bf2f(bv0[k]) * w0), bfc(bf2f(bv1[k]) * w1));
        }
    }
    __syncthreads();

    const int lane = tid & 63, w = tid >> 6;
    const int lm = lane & 15, lq = lane >> 4;
    const int tau0 = 16 * w + lq * 4;

    bf16x8 aG0 = ldfrag(Bn, 16 * w + lm, lq);
    bf16x8 aG1 = ldfrag(Bn, 16 * w + lm, 4 + lq);
    f32x4 g[4] = {};
    #pragma unroll
    for (int j = 0; j < 4; j++) {
        g[j] = __builtin_amdgcn_mfma_f32_16x16x32_bf16(aG0, ldfrag(Cn, 16 * j + lm, lq),     g[j], 0, 0, 0);
        g[j] = __builtin_amdgcn_mfma_f32_16x16x32_bf16(aG1, ldfrag(Cn, 16 * j + lm, 4 + lq), g[j], 0, 0, 0);
    }
    float ctau[4], dtau[4];
    *(float4*)&ctau[0] = *(const float4*)&cums[tau0];
    *(float4*)&dtau[0] = *(const float4*)&dts_s[tau0];
    s16x4 mp[4];
    #pragma unroll
    for (int j = 0; j < 4; j++) {
        int t = 16 * j + lm;
        float ct = cums[t];
        #pragma unroll
        for (int r = 0; r < 4; r++) {
            int tau = tau0 + r;
            float m = (t >= tau) ? g[j][r] * __expf(ct - ctau[r]) * dtau[r] : 0.f;
            mp[j][r] = (short)bfc(m);
        }
    }
    __syncthreads();
    #pragma unroll
    for (int j = 0; j < 4; j++)
        *(s16x4*)&Cn[swz(16 * j + lm, tau0)] = mp[j];   // MT[t][tau]
    __syncthreads();

    bf16x8 aY0 = ldfrag(Cn,  16 * w + lm, lq);
    bf16x8 aY1 = ldfrag(Cn,  16 * w + lm, 4 + lq);
    bf16x8 aS0 = ldfrag(BTw, 16 * w + lm, lq);
    bf16x8 aS1 = ldfrag(BTw, 16 * w + lm, 4 + lq);
    f32x4 yv[4] = {}, sv[4] = {};
    #pragma unroll
    for (int j = 0; j < 4; j++) {
        bf16x8 xf0 = ldfrag(Xt, 16 * j + lm, lq);
        bf16x8 xf1 = ldfrag(Xt, 16 * j + lm, 4 + lq);
        yv[j] = __builtin_amdgcn_mfma_f32_16x16x32_bf16(aY0, xf0, yv[j], 0, 0, 0);
        yv[j] = __builtin_amdgcn_mfma_f32_16x16x32_bf16(aY1, xf1, yv[j], 0, 0, 0);
        sv[j] = __builtin_amdgcn_mfma_f32_16x16x32_bf16(aS0, xf0, sv[j], 0, 0, 0);
        sv[j] = __builtin_amdgcn_mfma_f32_16x16x32_bf16(aS1, xf1, sv[j], 0, 0, 0);
    }
    const int mrow = 16 * w + lq * 4;
    #pragma unroll
    for (int j = 0; j < 4; j++)
        #pragma unroll
        for (int r = 0; r < 4; r++)
            ys[(size_t)(row0 + mrow + r) * D_INNER + h * HEADDIM + 16 * j + lm] = bfc(yv[j][r]);
    u16* sb = Schunk + (size_t)((b * NCHUNK + c) * NHEADS + h) * 4096;
    #pragma unroll
    for (int j = 0; j < 4; j++)
        #pragma unroll
        for (int r = 0; r < 4; r++)
            sb[(mrow + r) * 64 + 16 * j + lm] = bfc(sv[j][r]);
}

// ---------------------------------------------------------------------------
// Parallel prefix scan over chunk states. Grid = 64 (b,h) x 4 quarters.
// ---------------------------------------------------------------------------
__global__ __launch_bounds__(256) void ssd_state_scan_kernel(
    u16* __restrict__ Schunk, const float* __restrict__ adec)
{
    const int q  = blockIdx.x & 3;
    const int bh = blockIdx.x >> 2;
    const int b  = bh >> 3, h = bh & 7;
    const int base = q * 1024 + threadIdx.x * 4;

    u16x4 v[NCHUNK];
    float atot[NCHUNK];
    #pragma unroll
    for (int c = 0; c < NCHUNK; c++) {
        v[c] = *(const u16x4*)&Schunk[(size_t)((b * NCHUNK + c) * NHEADS + h) * 4096 + base];
        atot[c] = adec[(size_t)bh * SEQLEN + c * CHUNK + 63];
    }
    float run[4] = {0.f, 0.f, 0.f, 0.f};
    #pragma unroll
    for (int c = 0; c < NCHUNK; c++) {
        u16x4 pv;
        #pragma unroll
        for (int k = 0; k < 4; k++) pv[k] = bfc(run[k]);
        *(u16x4*)&Schunk[(size_t)((b * NCHUNK + c) * NHEADS + h) * 4096 + base] = pv;
        #pragma unroll
        for (int k = 0; k < 4; k++)
            run[k] = fmaf(atot[c], run[k], bf2f(v[c][k]));
    }
}

// ---------------------------------------------------------------------------
// Fused inter + gate + RMS partial sum. One block per (b, chunk, half, hpair):
// 32 rows x 2 heads (128 cols). 128 threads (2 waves). S prefetched to regs.
// ---------------------------------------------------------------------------
__global__ __launch_bounds__(128) void ssd_finish_kernel(
    const u16* __restrict__ xc, const u16* __restrict__ zx,
    const u16* __restrict__ Schunk, const float* __restrict__ adec,
    const float* __restrict__ Dp, const float* __restrict__ nw,
    u16* __restrict__ ys, float* __restrict__ ssum)
{
    const int hp   = blockIdx.x & 3;          // head pair
    const int half = (blockIdx.x >> 2) & 1;
    const int c    = (blockIdx.x >> 3) & 15;
    const int b    = blockIdx.x >> 7;
    const int h0   = hp * 2;
    const int tid  = threadIdx.x;
    const int row0 = b * SEQLEN + c * CHUNK + half * 32;

    __shared__ short Ct[32 * 64];   // [t][n] swizzled
    __shared__ short STs[64 * 64];  // [p][n] swizzled, per-head
    __shared__ float a_s[64];       // [hi][32]
    __shared__ float nw_s[128];

    // ---- prefetch both heads' S tiles into registers (overlaps C staging) ----
    u16x8 sp[2][4];
    {
        int n4 = (tid >> 3) * 4, p8 = (tid & 7) * 8;
        #pragma unroll
        for (int hi = 0; hi < 2; hi++) {
            const u16* sb = Schunk + (size_t)((b * NCHUNK + c) * NHEADS + h0 + hi) * 4096;
            #pragma unroll
            for (int k = 0; k < 4; k++)
                sp[hi][k] = *(const u16x8*)&sb[(n4 + k) * 64 + p8];
        }
    }
    {   // stage C (32 rows x 64 states), decay rows, norm weights
        int t2 = (tid >> 3) * 2, n8 = (tid & 7) * 8;
        const u16* r0 = xc + (size_t)(row0 + t2) * CONV_DIM + D_INNER + D_STATE;
        u16x8 v0 = *(const u16x8*)&r0[n8];
        u16x8 v1 = *(const u16x8*)&r0[CONV_DIM + n8];
        *(u16x8*)&Ct[swz(t2,     n8)] = v0;
        *(u16x8*)&Ct[swz(t2 + 1, n8)] = v1;
        if (tid < 16) {
            int hh = tid >> 3, t4 = (tid & 7) * 4;
            *(float4*)&a_s[hh * 32 + t4] = *(const float4*)
                &adec[(size_t)(b * NHEADS + h0 + hh) * SEQLEN + c * CHUNK + half * 32 + t4];
        }
        nw_s[tid] = nw[h0 * 64 + tid];
    }

    const int lane = tid & 63, w = tid >> 6;
    const int lm = lane & 15, lq = lane >> 4;
    const int trow = 16 * w + lq * 4;

    bf16x8 aC0, aC1;
    float ss[4] = {0.f, 0.f, 0.f, 0.f};

    for (int hi = 0; hi < 2; hi++) {
        const int h = h0 + hi;
        {   // stage S_h^T from regs: [n][p] -> LDS [p][n]
            int n4 = (tid >> 3) * 4, p8 = (tid & 7) * 8;
            #pragma unroll
            for (int k = 0; k < 8; k++) {
                wr2u(STs, p8 + k, n4,     sp[hi][0][k], sp[hi][1][k]);
                wr2u(STs, p8 + k, n4 + 2, sp[hi][2][k], sp[hi][3][k]);
            }
        }
        __syncthreads();
        if (hi == 0) {
            aC0 = ldfrag(Ct, 16 * w + lm, lq);
            aC1 = ldfrag(Ct, 16 * w + lm, 4 + lq);
        }
        f32x4 U[4] = {};
        #pragma unroll
        for (int j = 0; j < 4; j++) {
            U[j] = __builtin_amdgcn_mfma_f32_16x16x32_bf16(aC0, ldfrag(STs, 16 * j + lm, lq),     U[j], 0, 0, 0);
            U[j] = __builtin_amdgcn_mfma_f32_16x16x32_bf16(aC1, ldfrag(STs, 16 * j + lm, 4 + lq), U[j], 0, 0, 0);
        }
        float Dh = Dp[h];
        #pragma unroll
        for (int j = 0; j < 4; j++) {
            int col = h * 64 + 16 * j + lm;
            float nwv = nw_s[hi * 64 + 16 * j + lm];
            #pragma unroll
            for (int r = 0; r < 4; r++) {
                int row = trow + r;
                size_t grow = (size_t)(row0 + row);
                float a = a_s[hi * 32 + row];
                float u = U[j][r] * a
                        + bf2f(ys[grow * D_INNER + col])
                        + Dh * bf2f(xc[grow * CONV_DIM + col]);
                float zv = bf2f(zx[grow * ZXP + col]);
                float gt = zv / (1.f + expf(-zv));
                float v = u * gt;
                ss[r] = fmaf(v, v, ss[r]);
                ys[grow * D_INNER + col] = bfc(v * nwv);
            }
        }
        __syncthreads();
    }
    #pragma unroll
    for (int r = 0; r < 4; r++) {
        float s = ss[r];
        s += __shfl_xor(s, 1, 64); s += __shfl_xor(s, 2, 64);
        s += __shfl_xor(s, 4, 64); s += __shfl_xor(s, 8, 64);
        if (lm == 0)
            atomicAdd(&ssum[row0 + trow + r], s);
    }
}

// ---------------------------------------------------------------------------
extern "C" void kernel_launch(void* const* d_in, const int* in_sizes, int n_in,
                              void* d_out, int out_size, void* d_ws, size_t ws_size,
                              hipStream_t stream) {
    const float* x          = (const float*)d_in[0];
    const float* in_proj_w  = (const float*)d_in[1];
    const float* conv_w     = (const float*)d_in[2];
    const float* conv_b     = (const float*)d_in[3];
    const float* dt_bias    = (const float*)d_in[4];
    const float* A_log      = (const float*)d_in[5];
    const float* Dp         = (const float*)d_in[6];
    const float* norm_w     = (const float*)d_in[7];
    const float* out_proj_w = (const float*)d_in[8];
    float* out = (float*)d_out;

    u16*   buf_zx = (u16*)d_ws;                                      // 8192 x 1280 bf16
    u16*   buf_xc = buf_zx + (size_t)NROWS * ZXP;                    // 8192 x 640  bf16
    u16*   buf_ys = buf_xc + (size_t)NROWS * CONV_DIM;               // 8192 x 512  bf16
    u16*   buf_S  = buf_ys + (size_t)NROWS * D_INNER;                // 128*8*4096  bf16
    u16*   buf_hb = buf_S  + (size_t)BATCH * NCHUNK * NHEADS * 4096; // 8192 x 256  bf16
    u16*   buf_wi = buf_hb + (size_t)NROWS * D_MODEL;                // 2x1280x256  bf16
    u16*   buf_wo = buf_wi + (size_t)2 * ZXP * D_MODEL;              // 2x256x512   bf16
    float* buf_dt = (float*)(buf_wo + (size_t)2 * D_MODEL * D_INNER);// 8192 x 8    f32
    float* buf_a  = buf_dt + (size_t)NROWS * NHEADS;                 // 64 x 1024   f32
    float* buf_sc = buf_a  + (size_t)BATCH * NHEADS * SEQLEN;        // 8192        f32

    cast_all_kernel<<<(NX_C + NWI_C + NWO_C) / 256, 256, 0, stream>>>(
        x, in_proj_w, out_proj_w, buf_hb, buf_wi, buf_wo);

    for (int i = 0; i < 2; i++) {
        gemm_mfma<__hip_bfloat16, true><<<dim3(ZXP / 128, NROWS / 128), 256, 0, stream>>>(
            (const short*)buf_hb, (const short*)(buf_wi + (size_t)i * ZXP * D_MODEL),
            (__hip_bfloat16*)buf_zx, buf_dt, ZXP, D_MODEL, D_MODEL);

        conv_silu_kernel<<<(NROWS / 4) * 160 / 256, 256, 0, stream>>>(
            buf_zx, conv_w + (size_t)i * CONV_DIM * D_CONV,
            conv_b + (size_t)i * CONV_DIM, buf_xc);

        ssd_intra_kernel<<<BATCH * NCHUNK * NHEADS, 256, 0, stream>>>(
            buf_xc, buf_dt, dt_bias + i * NHEADS, A_log + i * NHEADS,
            buf_ys, buf_S, buf_a, buf_sc);

        ssd_state_scan_kernel<<<BATCH * NHEADS * 4, 256, 0, stream>>>(buf_S, buf_a);

        ssd_finish_kernel<<<BATCH * NCHUNK * 2 * 4, 128, 0, stream>>>(
            buf_xc, buf_zx, buf_S, buf_a, Dp + i * NHEADS,
            norm_w + (size_t)i * D_INNER, buf_ys, buf_sc);

        if (i == 0) {
            gemm_out<__hip_bfloat16><<<dim3(D_MODEL / 128, NROWS / 64), 256, 0, stream>>>(
                (const short*)buf_ys, (const short*)buf_wo,
                (__hip_bfloat16*)buf_hb, buf_sc, D_MODEL, D_INNER);
        } else {
            gemm_out<float><<<dim3(D_MODEL / 128, NROWS / 64), 256, 0, stream>>>(
                (const short*)buf_ys, (const short*)(buf_wo + (size_t)D_MODEL * D_INNER),
                out, buf_sc, D_MODEL, D_INNER);
        }
    }
}

// Round 10
// 209.417 us; speedup vs baseline: 1.0564x; 1.0564x over previous
//
#include <hip/hip_runtime.h>
#include <hip/hip_bf16.h>
#include <math.h>

#define D_MODEL   256
#define D_STATE   64
#define D_CONV    4
#define D_INNER   512
#define HEADDIM   64
#define NHEADS    8
#define CONV_DIM  640     // D_INNER + 2*D_STATE
#define D_IN_PROJ 1160    // 2*D_INNER + 2*D_STATE + NHEADS
#define ZXP       1280    // padded in_proj N (10 x 128 tiles)
#define SEQLEN    1024
#define BATCH     8
#define NROWS     8192    // BATCH * SEQLEN
#define EPS       1e-5f
#define CHUNK     64
#define NCHUNK    (SEQLEN / CHUNK)   // 16

typedef __attribute__((ext_vector_type(8))) short bf16x8;
typedef __attribute__((ext_vector_type(4))) short s16x4;
typedef __attribute__((ext_vector_type(8))) unsigned short u16x8;
typedef __attribute__((ext_vector_type(4))) unsigned short u16x4;
typedef __attribute__((ext_vector_type(4))) float f32x4;
typedef unsigned int u32;
typedef unsigned short u16;

__device__ __forceinline__ void cp16(const short* g, short* l) {
    __builtin_amdgcn_global_load_lds((const __attribute__((address_space(1))) u32*)g,
                                     (__attribute__((address_space(3))) u32*)l, 16, 0, 0);
}
__device__ __forceinline__ u16 bfc(float f) {
    union { __hip_bfloat16 h; u16 u; } cv;
    cv.h = __float2bfloat16(f);
    return cv.u;
}
__device__ __forceinline__ float bf2f(u16 u) {
    union { u32 v; float f; } cv;
    cv.v = ((u32)u) << 16;
    return cv.f;
}
__device__ __forceinline__ void store_out(float* p, float v) { *p = v; }
__device__ __forceinline__ void store_out(__hip_bfloat16* p, float v) { *p = __float2bfloat16(v); }

// 64-col bf16 LDS tile, XOR-octet swizzle
__device__ __forceinline__ int swz(int row, int col) {
    return row * 64 + (((col & 56) ^ ((row & 7) << 3)) | (col & 7));
}
__device__ __forceinline__ bf16x8 ldfrag(const short* base, int row, int oct) {
    return *(const bf16x8*)&base[row * 64 + ((oct * 8) ^ ((row & 7) * 8))];
}
__device__ __forceinline__ void wr2u(short* base, int row, int col2, u16 a, u16 b) {
    int idx = row * 64 + (((col2 & 56) ^ ((row & 7) << 3)) | (col2 & 6));
    *(u32*)&base[idx] = (u32)a | ((u32)b << 16);
}

// ---------------------------------------------------------------------------
// C[m,n] = A[m,:] . W[n,:]  (bf16, fp32 acc). Tile 128x128, BK=32, 4 waves.
// WITH_DT: spill raw cols [D_IN_PROJ-8, D_IN_PROJ) to fp32 dtout.
// SCALE:  multiply output row m by rsqrt(sc[m]/512+eps) (RMSNorm epilogue).
// ---------------------------------------------------------------------------
template <typename OUT, bool WITH_DT, bool SCALE>
__global__ __launch_bounds__(256) void gemm_mfma(const short* __restrict__ A,
                                                 const short* __restrict__ W,
                                                 OUT* __restrict__ C,
                                                 float* __restrict__ dtout,
                                                 const float* __restrict__ sc,
                                                 int N, int K, int lda) {
    __shared__ short As[128 * 32];
    __shared__ short Ws[128 * 32];
    const int tid  = threadIdx.x;
    const int m0   = blockIdx.y * 128;
    const int n0   = blockIdx.x * 128;
    const int wave = tid >> 6;
    const int lane = tid & 63;
    const int wm   = (wave & 1) * 64;
    const int wn   = (wave >> 1) * 64;
    const int lm   = lane & 15;
    const int lq   = lane >> 4;

    const int sr = tid >> 2;
    const int sk = (tid & 3) * 8;
    const short* ga = A + (size_t)(m0 + sr) * lda + sk;
    const short* gw = W + (size_t)(n0 + sr) * K + sk;
    short* la = &As[tid * 8];
    short* lw = &Ws[tid * 8];
    const size_t ga2 = (size_t)64 * lda;
    const size_t gw2 = (size_t)64 * K;

    f32x4 acc[4][4] = {};

    for (int k0 = 0; k0 < K; k0 += 32) {
        cp16(ga,       la);
        cp16(ga + ga2, la + 64 * 32);
        cp16(gw,       lw);
        cp16(gw + gw2, lw + 64 * 32);
        ga += 32; gw += 32;
        __syncthreads();
        bf16x8 af[4], bfr[4];
        #pragma unroll
        for (int i = 0; i < 4; i++) {
            af[i]  = *(const bf16x8*)&As[(wm + i * 16 + lm) * 32 + lq * 8];
            bfr[i] = *(const bf16x8*)&Ws[(wn + i * 16 + lm) * 32 + lq * 8];
        }
        #pragma unroll
        for (int i = 0; i < 4; i++)
            #pragma unroll
            for (int j = 0; j < 4; j++)
                acc[i][j] = __builtin_amdgcn_mfma_f32_16x16x32_bf16(af[i], bfr[j], acc[i][j], 0, 0, 0);
        __syncthreads();
    }
    #pragma unroll
    for (int i = 0; i < 4; i++)
        #pragma unroll
        for (int r = 0; r < 4; r++) {
            int m = m0 + wm + i * 16 + lq * 4 + r;
            float scl = SCALE ? rsqrtf(sc[m] * (1.f / (float)D_INNER) + EPS) : 1.f;
            #pragma unroll
            for (int j = 0; j < 4; j++) {
                int n = n0 + wn + j * 16 + lm;
                float v = acc[i][j][r];
                store_out(&C[(size_t)m * N + n], v * scl);
                if (WITH_DT) {
                    if (n >= D_IN_PROJ - NHEADS && n < D_IN_PROJ)
                        dtout[(size_t)m * NHEADS + (n - (D_IN_PROJ - NHEADS))] = v;
                }
            }
        }
}

// ---------------------------------------------------------------------------
// Fused casts: x -> bf16, in_proj_w -> padded bf16, out_proj_w -> bf16.
// ---------------------------------------------------------------------------
#define NX_C  (NROWS * D_MODEL)
#define NWI_C (2 * ZXP * D_MODEL)
#define NWO_C (2 * D_MODEL * D_INNER)
__global__ __launch_bounds__(256) void cast_all_kernel(
    const float* __restrict__ x, const float* __restrict__ wi,
    const float* __restrict__ wo,
    u16* __restrict__ xb, u16* __restrict__ wib, u16* __restrict__ wob)
{
    int idx = blockIdx.x * 256 + threadIdx.x;
    if (idx < NX_C) { xb[idx] = bfc(x[idx]); return; }
    idx -= NX_C;
    if (idx < NWI_C) {
        int k = idx & 255;
        int rb = idx >> 8;
        int r = rb % ZXP;
        int blk = rb / ZXP;
        float v = (r < D_IN_PROJ)
            ? wi[(size_t)blk * D_IN_PROJ * D_MODEL + (size_t)r * D_MODEL + k] : 0.f;
        wib[idx] = bfc(v);
        return;
    }
    idx -= NWI_C;
    wob[idx] = bfc(wo[idx]);
}

// ---------------------------------------------------------------------------
// Depthwise causal conv (width 4) + bias + SiLU; 4 rows x 4 channels / thread.
// ---------------------------------------------------------------------------
__global__ __launch_bounds__(256) void conv_silu_kernel(const u16* __restrict__ zx,
                                                        const float* __restrict__ cw,
                                                        const float* __restrict__ cb,
                                                        u16* __restrict__ out) {
    int idx = blockIdx.x * 256 + threadIdx.x;   // (NROWS/4) * 160
    int c4  = (idx % 160) * 4;
    int r4  = (idx / 160) * 4;
    int l4  = r4 & (SEQLEN - 1);
    float wt[4][4];     // [k][tap]
    #pragma unroll
    for (int k = 0; k < 4; k++)
        *(float4*)&wt[k][0] = *(const float4*)&cw[(c4 + k) * 4];
    float4 cbv = *(const float4*)&cb[c4];
    float cbk[4] = {cbv.x, cbv.y, cbv.z, cbv.w};

    const u16* base = zx + (size_t)r4 * ZXP + D_INNER + c4;
    u16x4 hrow[7];
    #pragma unroll
    for (int k = 0; k < 3; k++) {
        if (l4 != 0) hrow[k] = *(const u16x4*)&base[(k - 3) * ZXP];
        else { hrow[k][0] = 0; hrow[k][1] = 0; hrow[k][2] = 0; hrow[k][3] = 0; }
    }
    #pragma unroll
    for (int k = 3; k < 7; k++)
        hrow[k] = *(const u16x4*)&base[(k - 3) * ZXP];

    #pragma unroll
    for (int rr = 0; rr < 4; rr++) {
        u16x4 o;
        #pragma unroll
        for (int k = 0; k < 4; k++) {
            float acc = cbk[k];
            #pragma unroll
            for (int tap = 0; tap < 4; tap++)
                acc = fmaf(bf2f(hrow[rr + tap][k]), wt[k][tap], acc);
            float s = acc / (1.f + expf(-acc));
            o[k] = bfc(s);
        }
        *(u16x4*)&out[(size_t)(r4 + rr) * CONV_DIM + c4] = o;
    }
}

// ---------------------------------------------------------------------------
// SSD intra-chunk, MFMA. One block per (b, chunk, head), 4 waves.
// Outputs: y_intra (bf16), Schunk (bf16 [n][p]), adec (fp32).
// ---------------------------------------------------------------------------
__global__ __launch_bounds__(256) void ssd_intra_kernel(
    const u16* __restrict__ xc, const float* __restrict__ dtbuf,
    const float* __restrict__ dt_bias, const float* __restrict__ A_log,
    u16* __restrict__ ys, u16* __restrict__ Schunk,
    float* __restrict__ adec, float* __restrict__ ssum)
{
    const int h   = blockIdx.x & 7;
    const int c   = (blockIdx.x >> 3) & 15;
    const int b   = blockIdx.x >> 7;
    const int tid = threadIdx.x;
    const int row0 = b * SEQLEN + c * CHUNK;

    if (tid < 8) ssum[blockIdx.x * 8 + tid] = 0.f;

    __shared__ short Xt[64 * 64];    // [p][t]
    __shared__ short Bn[64 * 64];    // [t][n]
    __shared__ short Cn[64 * 64];    // [t][n]  -> reused as MT [t][tau]
    __shared__ short BTw[64 * 64];   // [n][t], w-folded
    __shared__ float cums[64], dts_s[64], ws_s[64];

    if (tid < 64) {
        const float A = -expf(A_log[h]);
        float raw = dtbuf[(size_t)(row0 + tid) * NHEADS + h] + dt_bias[h];
        float dtv = (raw > 20.f) ? raw : log1pf(expf(raw));
        float v = dtv * A;
        #pragma unroll
        for (int off = 1; off < 64; off <<= 1) {
            float o = __shfl_up(v, off, 64);
            if (tid >= off) v += o;
        }
        float tot = __shfl(v, 63, 64);
        cums[tid]  = v;
        dts_s[tid] = dtv;
        ws_s[tid]  = expf(tot - v) * dtv;
        adec[(size_t)(b * NHEADS + h) * SEQLEN + c * CHUNK + tid] = expf(v);
    }
    __syncthreads();

    {
        const int t2 = (tid >> 3) * 2;
        const int c8 = (tid & 7) * 8;
        const u16* r0 = xc + (size_t)(row0 + t2) * CONV_DIM;
        const u16* r1 = r0 + CONV_DIM;
        u16x8 xv0 = *(const u16x8*)&r0[h * HEADDIM + c8];
        u16x8 xv1 = *(const u16x8*)&r1[h * HEADDIM + c8];
        u16x8 bv0 = *(const u16x8*)&r0[D_INNER + c8];
        u16x8 bv1 = *(const u16x8*)&r1[D_INNER + c8];
        u16x8 cv0 = *(const u16x8*)&r0[D_INNER + D_STATE + c8];
        u16x8 cv1 = *(const u16x8*)&r1[D_INNER + D_STATE + c8];
        *(u16x8*)&Bn[swz(t2,     c8)] = bv0;
        *(u16x8*)&Bn[swz(t2 + 1, c8)] = bv1;
        *(u16x8*)&Cn[swz(t2,     c8)] = cv0;
        *(u16x8*)&Cn[swz(t2 + 1, c8)] = cv1;
        float w0 = ws_s[t2], w1 = ws_s[t2 + 1];
        #pragma unroll
        for (int k = 0; k < 8; k++) {
            wr2u(Xt,  c8 + k, t2, xv0[k], xv1[k]);
            wr2u(BTw, c8 + k, t2, bfc(bf2f(bv0[k]) * w0), bfc(bf2f(bv1[k]) * w1));
        }
    }
    __syncthreads();

    const int lane = tid & 63, w = tid >> 6;
    const int lm = lane & 15, lq = lane >> 4;
    const int tau0 = 16 * w + lq * 4;

    bf16x8 aG0 = ldfrag(Bn, 16 * w + lm, lq);
    bf16x8 aG1 = ldfrag(Bn, 16 * w + lm, 4 + lq);
    f32x4 g[4] = {};
    #pragma unroll
    for (int j = 0; j < 4; j++) {
        g[j] = __builtin_amdgcn_mfma_f32_16x16x32_bf16(aG0, ldfrag(Cn, 16 * j + lm, lq),     g[j], 0, 0, 0);
        g[j] = __builtin_amdgcn_mfma_f32_16x16x32_bf16(aG1, ldfrag(Cn, 16 * j + lm, 4 + lq), g[j], 0, 0, 0);
    }
    float ctau[4], dtau[4];
    *(float4*)&ctau[0] = *(const float4*)&cums[tau0];
    *(float4*)&dtau[0] = *(const float4*)&dts_s[tau0];
    s16x4 mp[4];
    #pragma unroll
    for (int j = 0; j < 4; j++) {
        int t = 16 * j + lm;
        float ct = cums[t];
        #pragma unroll
        for (int r = 0; r < 4; r++) {
            int tau = tau0 + r;
            float m = (t >= tau) ? g[j][r] * __expf(ct - ctau[r]) * dtau[r] : 0.f;
            mp[j][r] = (short)bfc(m);
        }
    }
    __syncthreads();
    #pragma unroll
    for (int j = 0; j < 4; j++)
        *(s16x4*)&Cn[swz(16 * j + lm, tau0)] = mp[j];   // MT[t][tau]
    __syncthreads();

    bf16x8 aY0 = ldfrag(Cn,  16 * w + lm, lq);
    bf16x8 aY1 = ldfrag(Cn,  16 * w + lm, 4 + lq);
    bf16x8 aS0 = ldfrag(BTw, 16 * w + lm, lq);
    bf16x8 aS1 = ldfrag(BTw, 16 * w + lm, 4 + lq);
    f32x4 yv[4] = {}, sv[4] = {};
    #pragma unroll
    for (int j = 0; j < 4; j++) {
        bf16x8 xf0 = ldfrag(Xt, 16 * j + lm, lq);
        bf16x8 xf1 = ldfrag(Xt, 16 * j + lm, 4 + lq);
        yv[j] = __builtin_amdgcn_mfma_f32_16x16x32_bf16(aY0, xf0, yv[j], 0, 0, 0);
        yv[j] = __builtin_amdgcn_mfma_f32_16x16x32_bf16(aY1, xf1, yv[j], 0, 0, 0);
        sv[j] = __builtin_amdgcn_mfma_f32_16x16x32_bf16(aS0, xf0, sv[j], 0, 0, 0);
        sv[j] = __builtin_amdgcn_mfma_f32_16x16x32_bf16(aS1, xf1, sv[j], 0, 0, 0);
    }
    const int mrow = 16 * w + lq * 4;
    #pragma unroll
    for (int j = 0; j < 4; j++)
        #pragma unroll
        for (int r = 0; r < 4; r++)
            ys[(size_t)(row0 + mrow + r) * D_INNER + h * HEADDIM + 16 * j + lm] = bfc(yv[j][r]);
    u16* sb = Schunk + (size_t)((b * NCHUNK + c) * NHEADS + h) * 4096;
    #pragma unroll
    for (int j = 0; j < 4; j++)
        #pragma unroll
        for (int r = 0; r < 4; r++)
            sb[(mrow + r) * 64 + 16 * j + lm] = bfc(sv[j][r]);
}

// ---------------------------------------------------------------------------
// Parallel prefix scan over chunk states. Grid = 64 (b,h) x 4 quarters,
// 256 threads; each thread owns 4 state elements, prefetches all 16 chunk
// values (independent of the recurrence), runs the chain in registers.
// ---------------------------------------------------------------------------
__global__ __launch_bounds__(256) void ssd_state_scan_kernel(
    u16* __restrict__ Schunk, const float* __restrict__ adec)
{
    const int q  = blockIdx.x & 3;
    const int bh = blockIdx.x >> 2;
    const int b  = bh >> 3, h = bh & 7;
    const int base = q * 1024 + threadIdx.x * 4;

    u16x4 v[NCHUNK];
    float atot[NCHUNK];
    #pragma unroll
    for (int c = 0; c < NCHUNK; c++) {
        v[c] = *(const u16x4*)&Schunk[(size_t)((b * NCHUNK + c) * NHEADS + h) * 4096 + base];
        atot[c] = adec[(size_t)bh * SEQLEN + c * CHUNK + 63];
    }
    float run[4] = {0.f, 0.f, 0.f, 0.f};
    #pragma unroll
    for (int c = 0; c < NCHUNK; c++) {
        u16x4 pv;
        #pragma unroll
        for (int k = 0; k < 4; k++) pv[k] = bfc(run[k]);
        *(u16x4*)&Schunk[(size_t)((b * NCHUNK + c) * NHEADS + h) * 4096 + base] = pv;
        #pragma unroll
        for (int k = 0; k < 4; k++)
            run[k] = fmaf(atot[c], run[k], bf2f(v[c][k]));
    }
}

// ---------------------------------------------------------------------------
// Fused inter + gate + RMS partial sum. One block per (b, chunk, half, hpair):
// 32 rows x 2 heads (128 cols). 128 threads (2 waves). ys updated in place
// (v*nw bf16, unnormalized); row sum-of-squares accumulated via atomicAdd.
// ---------------------------------------------------------------------------
__global__ __launch_bounds__(128) void ssd_finish_kernel(
    const u16* __restrict__ xc, const u16* __restrict__ zx,
    const u16* __restrict__ Schunk, const float* __restrict__ adec,
    const float* __restrict__ Dp, const float* __restrict__ nw,
    u16* __restrict__ ys, float* __restrict__ ssum)
{
    const int hp   = blockIdx.x & 3;          // head pair
    const int half = (blockIdx.x >> 2) & 1;
    const int c    = (blockIdx.x >> 3) & 15;
    const int b    = blockIdx.x >> 7;
    const int h0   = hp * 2;
    const int tid  = threadIdx.x;
    const int row0 = b * SEQLEN + c * CHUNK + half * 32;

    __shared__ short Ct[32 * 64];   // [t][n] swizzled
    __shared__ short STs[64 * 64];  // [p][n] swizzled, per-head
    __shared__ float a_s[64];       // [hi][32]
    __shared__ float nw_s[128];

    {   // stage C (32 rows x 64 states), decay rows, norm weights
        int t2 = (tid >> 3) * 2, n8 = (tid & 7) * 8;
        const u16* r0 = xc + (size_t)(row0 + t2) * CONV_DIM + D_INNER + D_STATE;
        u16x8 v0 = *(const u16x8*)&r0[n8];
        u16x8 v1 = *(const u16x8*)&r0[CONV_DIM + n8];
        *(u16x8*)&Ct[swz(t2,     n8)] = v0;
        *(u16x8*)&Ct[swz(t2 + 1, n8)] = v1;
        if (tid < 16) {
            int hh = tid >> 3, t4 = (tid & 7) * 4;
            *(float4*)&a_s[hh * 32 + t4] = *(const float4*)
                &adec[(size_t)(b * NHEADS + h0 + hh) * SEQLEN + c * CHUNK + half * 32 + t4];
        }
        nw_s[tid] = nw[h0 * 64 + tid];
    }

    const int lane = tid & 63, w = tid >> 6;
    const int lm = lane & 15, lq = lane >> 4;
    const int trow = 16 * w + lq * 4;

    bf16x8 aC0, aC1;
    float ss[4] = {0.f, 0.f, 0.f, 0.f};

    for (int hi = 0; hi < 2; hi++) {
        const int h = h0 + hi;
        {   // stage S_h^T: global [n][p] -> LDS [p][n]
            const u16* sb = Schunk + (size_t)((b * NCHUNK + c) * NHEADS + h) * 4096;
            int n4 = (tid >> 3) * 4, p8 = (tid & 7) * 8;
            u16x8 s0 = *(const u16x8*)&sb[(n4 + 0) * 64 + p8];
            u16x8 s1 = *(const u16x8*)&sb[(n4 + 1) * 64 + p8];
            u16x8 s2 = *(const u16x8*)&sb[(n4 + 2) * 64 + p8];
            u16x8 s3 = *(const u16x8*)&sb[(n4 + 3) * 64 + p8];
            #pragma unroll
            for (int k = 0; k < 8; k++) {
                wr2u(STs, p8 + k, n4,     s0[k], s1[k]);
                wr2u(STs, p8 + k, n4 + 2, s2[k], s3[k]);
            }
        }
        __syncthreads();
        if (hi == 0) {
            aC0 = ldfrag(Ct, 16 * w + lm, lq);
            aC1 = ldfrag(Ct, 16 * w + lm, 4 + lq);
        }
        f32x4 U[4] = {};
        #pragma unroll
        for (int j = 0; j < 4; j++) {
            U[j] = __builtin_amdgcn_mfma_f32_16x16x32_bf16(aC0, ldfrag(STs, 16 * j + lm, lq),     U[j], 0, 0, 0);
            U[j] = __builtin_amdgcn_mfma_f32_16x16x32_bf16(aC1, ldfrag(STs, 16 * j + lm, 4 + lq), U[j], 0, 0, 0);
        }
        float Dh = Dp[h];
        #pragma unroll
        for (int j = 0; j < 4; j++) {
            int col = h * 64 + 16 * j + lm;
            float nwv = nw_s[hi * 64 + 16 * j + lm];
            #pragma unroll
            for (int r = 0; r < 4; r++) {
                int row = trow + r;
                size_t grow = (size_t)(row0 + row);
                float a = a_s[hi * 32 + row];
                float u = U[j][r] * a
                        + bf2f(ys[grow * D_INNER + col])
                        + Dh * bf2f(xc[grow * CONV_DIM + col]);
                float zv = bf2f(zx[grow * ZXP + col]);
                float gt = zv / (1.f + expf(-zv));
                float v = u * gt;
                ss[r] = fmaf(v, v, ss[r]);
                ys[grow * D_INNER + col] = bfc(v * nwv);
            }
        }
        __syncthreads();
    }
    #pragma unroll
    for (int r = 0; r < 4; r++) {
        float s = ss[r];
        s += __shfl_xor(s, 1, 64); s += __shfl_xor(s, 2, 64);
        s += __shfl_xor(s, 4, 64); s += __shfl_xor(s, 8, 64);
        if (lm == 0)
            atomicAdd(&ssum[row0 + trow + r], s);
    }
}

// ---------------------------------------------------------------------------
extern "C" void kernel_launch(void* const* d_in, const int* in_sizes, int n_in,
                              void* d_out, int out_size, void* d_ws, size_t ws_size,
                              hipStream_t stream) {
    const float* x          = (const float*)d_in[0];
    const float* in_proj_w  = (const float*)d_in[1];
    const float* conv_w     = (const float*)d_in[2];
    const float* conv_b     = (const float*)d_in[3];
    const float* dt_bias    = (const float*)d_in[4];
    const float* A_log      = (const float*)d_in[5];
    const float* Dp         = (const float*)d_in[6];
    const float* norm_w     = (const float*)d_in[7];
    const float* out_proj_w = (const float*)d_in[8];
    float* out = (float*)d_out;

    u16*   buf_zx = (u16*)d_ws;                                      // 8192 x 1280 bf16
    u16*   buf_xc = buf_zx + (size_t)NROWS * ZXP;                    // 8192 x 640  bf16
    u16*   buf_ys = buf_xc + (size_t)NROWS * CONV_DIM;               // 8192 x 512  bf16
    u16*   buf_S  = buf_ys + (size_t)NROWS * D_INNER;                // 128*8*4096  bf16
    u16*   buf_hb = buf_S  + (size_t)BATCH * NCHUNK * NHEADS * 4096; // 8192 x 256  bf16
    u16*   buf_wi = buf_hb + (size_t)NROWS * D_MODEL;                // 2x1280x256  bf16
    u16*   buf_wo = buf_wi + (size_t)2 * ZXP * D_MODEL;              // 2x256x512   bf16
    float* buf_dt = (float*)(buf_wo + (size_t)2 * D_MODEL * D_INNER);// 8192 x 8    f32
    float* buf_a  = buf_dt + (size_t)NROWS * NHEADS;                 // 64 x 1024   f32
    float* buf_sc = buf_a  + (size_t)BATCH * NHEADS * SEQLEN;        // 8192        f32

    cast_all_kernel<<<(NX_C + NWI_C + NWO_C) / 256, 256, 0, stream>>>(
        x, in_proj_w, out_proj_w, buf_hb, buf_wi, buf_wo);

    for (int i = 0; i < 2; i++) {
        gemm_mfma<__hip_bfloat16, true, false><<<dim3(ZXP / 128, NROWS / 128), 256, 0, stream>>>(
            (const short*)buf_hb, (const short*)(buf_wi + (size_t)i * ZXP * D_MODEL),
            (__hip_bfloat16*)buf_zx, buf_dt, nullptr, ZXP, D_MODEL, D_MODEL);

        conv_silu_kernel<<<(NROWS / 4) * 160 / 256, 256, 0, stream>>>(
            buf_zx, conv_w + (size_t)i * CONV_DIM * D_CONV,
            conv_b + (size_t)i * CONV_DIM, buf_xc);

        ssd_intra_kernel<<<BATCH * NCHUNK * NHEADS, 256, 0, stream>>>(
            buf_xc, buf_dt, dt_bias + i * NHEADS, A_log + i * NHEADS,
            buf_ys, buf_S, buf_a, buf_sc);

        ssd_state_scan_kernel<<<BATCH * NHEADS * 4, 256, 0, stream>>>(buf_S, buf_a);

        ssd_finish_kernel<<<BATCH * NCHUNK * 2 * 4, 128, 0, stream>>>(
            buf_xc, buf_zx, buf_S, buf_a, Dp + i * NHEADS,
            norm_w + (size_t)i * D_INNER, buf_ys, buf_sc);

        if (i == 0) {
            gemm_mfma<__hip_bfloat16, false, true><<<dim3(D_MODEL / 128, NROWS / 128), 256, 0, stream>>>(
                (const short*)buf_ys, (const short*)buf_wo,
                (__hip_bfloat16*)buf_hb, nullptr, buf_sc, D_MODEL, D_INNER, D_INNER);
        } else {
            gemm_mfma<float, false, true><<<dim3(D_MODEL / 128, NROWS / 128), 256, 0, stream>>>(
                (const short*)buf_ys, (const short*)(buf_wo + (size_t)D_MODEL * D_INNER),
                out, nullptr, buf_sc, D_MODEL, D_INNER, D_INNER);
        }
    }
}

// Round 12
// 203.880 us; speedup vs baseline: 1.0851x; 1.0272x over previous
//
#include <hip/hip_runtime.h>
#include <hip/hip_bf16.h>
#include <math.h>

#define D_MODEL   256
#define D_STATE   64
#define D_CONV    4
#define D_INNER   512
#define HEADDIM   64
#define NHEADS    8
#define CONV_DIM  640     // D_INNER + 2*D_STATE
#define D_IN_PROJ 1160    // 2*D_INNER + 2*D_STATE + NHEADS
#define ZXP       1280    // padded in_proj N (10 x 128 tiles)
#define SEQLEN    1024
#define BATCH     8
#define NROWS     8192    // BATCH * SEQLEN
#define EPS       1e-5f
#define CHUNK     64
#define NCHUNK    (SEQLEN / CHUNK)   // 16

typedef __attribute__((ext_vector_type(8))) short bf16x8;
typedef __attribute__((ext_vector_type(4))) short s16x4;
typedef __attribute__((ext_vector_type(8))) unsigned short u16x8;
typedef __attribute__((ext_vector_type(4))) unsigned short u16x4;
typedef __attribute__((ext_vector_type(4))) float f32x4;
typedef unsigned int u32;
typedef unsigned short u16;

__device__ __forceinline__ void cp16(const short* g, short* l) {
    __builtin_amdgcn_global_load_lds((const __attribute__((address_space(1))) u32*)g,
                                     (__attribute__((address_space(3))) u32*)l, 16, 0, 0);
}
__device__ __forceinline__ u16 bfc(float f) {
    union { __hip_bfloat16 h; u16 u; } cv;
    cv.h = __float2bfloat16(f);
    return cv.u;
}
__device__ __forceinline__ float bf2f(u16 u) {
    union { u32 v; float f; } cv;
    cv.v = ((u32)u) << 16;
    return cv.f;
}
__device__ __forceinline__ void store_out(float* p, float v) { *p = v; }
__device__ __forceinline__ void store_out(__hip_bfloat16* p, float v) { *p = __float2bfloat16(v); }

// 64-col bf16 LDS tile, XOR-octet swizzle
__device__ __forceinline__ int swz(int row, int col) {
    return row * 64 + (((col & 56) ^ ((row & 7) << 3)) | (col & 7));
}
__device__ __forceinline__ bf16x8 ldfrag(const short* base, int row, int oct) {
    return *(const bf16x8*)&base[row * 64 + ((oct * 8) ^ ((row & 7) * 8))];
}
__device__ __forceinline__ void wr2u(short* base, int row, int col2, u16 a, u16 b) {
    int idx = row * 64 + (((col2 & 56) ^ ((row & 7) << 3)) | (col2 & 6));
    *(u32*)&base[idx] = (u32)a | ((u32)b << 16);
}

// ---------------------------------------------------------------------------
// C[m,n] = A[m,:] . W[n,:]  (bf16, fp32 acc). Tile 128x128, BK=32, 4 waves.
// WITH_DT: spill raw cols [D_IN_PROJ-8, D_IN_PROJ) to fp32 dtout.
// SCALE:  multiply output row m by rsqrt(sc[m]/512+eps) (RMSNorm epilogue).
// ---------------------------------------------------------------------------
template <typename OUT, bool WITH_DT, bool SCALE>
__global__ __launch_bounds__(256) void gemm_mfma(const short* __restrict__ A,
                                                 const short* __restrict__ W,
                                                 OUT* __restrict__ C,
                                                 float* __restrict__ dtout,
                                                 const float* __restrict__ sc,
                                                 int N, int K, int lda) {
    __shared__ short As[128 * 32];
    __shared__ short Ws[128 * 32];
    const int tid  = threadIdx.x;
    const int m0   = blockIdx.y * 128;
    const int n0   = blockIdx.x * 128;
    const int wave = tid >> 6;
    const int lane = tid & 63;
    const int wm   = (wave & 1) * 64;
    const int wn   = (wave >> 1) * 64;
    const int lm   = lane & 15;
    const int lq   = lane >> 4;

    const int sr = tid >> 2;
    const int sk = (tid & 3) * 8;
    const short* ga = A + (size_t)(m0 + sr) * lda + sk;
    const short* gw = W + (size_t)(n0 + sr) * K + sk;
    short* la = &As[tid * 8];
    short* lw = &Ws[tid * 8];
    const size_t ga2 = (size_t)64 * lda;
    const size_t gw2 = (size_t)64 * K;

    f32x4 acc[4][4] = {};

    for (int k0 = 0; k0 < K; k0 += 32) {
        cp16(ga,       la);
        cp16(ga + ga2, la + 64 * 32);
        cp16(gw,       lw);
        cp16(gw + gw2, lw + 64 * 32);
        ga += 32; gw += 32;
        __syncthreads();
        bf16x8 af[4], bfr[4];
        #pragma unroll
        for (int i = 0; i < 4; i++) {
            af[i]  = *(const bf16x8*)&As[(wm + i * 16 + lm) * 32 + lq * 8];
            bfr[i] = *(const bf16x8*)&Ws[(wn + i * 16 + lm) * 32 + lq * 8];
        }
        #pragma unroll
        for (int i = 0; i < 4; i++)
            #pragma unroll
            for (int j = 0; j < 4; j++)
                acc[i][j] = __builtin_amdgcn_mfma_f32_16x16x32_bf16(af[i], bfr[j], acc[i][j], 0, 0, 0);
        __syncthreads();
    }
    #pragma unroll
    for (int i = 0; i < 4; i++)
        #pragma unroll
        for (int r = 0; r < 4; r++) {
            int m = m0 + wm + i * 16 + lq * 4 + r;
            float scl = SCALE ? rsqrtf(sc[m] * (1.f / (float)D_INNER) + EPS) : 1.f;
            #pragma unroll
            for (int j = 0; j < 4; j++) {
                int n = n0 + wn + j * 16 + lm;
                float v = acc[i][j][r];
                store_out(&C[(size_t)m * N + n], v * scl);
                if (WITH_DT) {
                    if (n >= D_IN_PROJ - NHEADS && n < D_IN_PROJ)
                        dtout[(size_t)m * NHEADS + (n - (D_IN_PROJ - NHEADS))] = v;
                }
            }
        }
}

// ---------------------------------------------------------------------------
// Fused casts: x -> bf16, in_proj_w -> padded bf16, out_proj_w -> bf16.
// ---------------------------------------------------------------------------
#define NX_C  (NROWS * D_MODEL)
#define NWI_C (2 * ZXP * D_MODEL)
#define NWO_C (2 * D_MODEL * D_INNER)
__global__ __launch_bounds__(256) void cast_all_kernel(
    const float* __restrict__ x, const float* __restrict__ wi,
    const float* __restrict__ wo,
    u16* __restrict__ xb, u16* __restrict__ wib, u16* __restrict__ wob)
{
    int idx = blockIdx.x * 256 + threadIdx.x;
    if (idx < NX_C) { xb[idx] = bfc(x[idx]); return; }
    idx -= NX_C;
    if (idx < NWI_C) {
        int k = idx & 255;
        int rb = idx >> 8;
        int r = rb % ZXP;
        int blk = rb / ZXP;
        float v = (r < D_IN_PROJ)
            ? wi[(size_t)blk * D_IN_PROJ * D_MODEL + (size_t)r * D_MODEL + k] : 0.f;
        wib[idx] = bfc(v);
        return;
    }
    idx -= NWI_C;
    wob[idx] = bfc(wo[idx]);
}

// ---------------------------------------------------------------------------
// Depthwise causal conv (width 4) + bias + SiLU; 4 rows x 4 channels / thread.
// ---------------------------------------------------------------------------
__global__ __launch_bounds__(256) void conv_silu_kernel(const u16* __restrict__ zx,
                                                        const float* __restrict__ cw,
                                                        const float* __restrict__ cb,
                                                        u16* __restrict__ out) {
    int idx = blockIdx.x * 256 + threadIdx.x;   // (NROWS/4) * 160
    int c4  = (idx % 160) * 4;
    int r4  = (idx / 160) * 4;
    int l4  = r4 & (SEQLEN - 1);
    float wt[4][4];     // [k][tap]
    #pragma unroll
    for (int k = 0; k < 4; k++)
        *(float4*)&wt[k][0] = *(const float4*)&cw[(c4 + k) * 4];
    float4 cbv = *(const float4*)&cb[c4];
    float cbk[4] = {cbv.x, cbv.y, cbv.z, cbv.w};

    const u16* base = zx + (size_t)r4 * ZXP + D_INNER + c4;
    u16x4 hrow[7];
    #pragma unroll
    for (int k = 0; k < 3; k++) {
        if (l4 != 0) hrow[k] = *(const u16x4*)&base[(k - 3) * ZXP];
        else { hrow[k][0] = 0; hrow[k][1] = 0; hrow[k][2] = 0; hrow[k][3] = 0; }
    }
    #pragma unroll
    for (int k = 3; k < 7; k++)
        hrow[k] = *(const u16x4*)&base[(k - 3) * ZXP];

    #pragma unroll
    for (int rr = 0; rr < 4; rr++) {
        u16x4 o;
        #pragma unroll
        for (int k = 0; k < 4; k++) {
            float acc = cbk[k];
            #pragma unroll
            for (int tap = 0; tap < 4; tap++)
                acc = fmaf(bf2f(hrow[rr + tap][k]), wt[k][tap], acc);
            float s = acc / (1.f + expf(-acc));
            o[k] = bfc(s);
        }
        *(u16x4*)&out[(size_t)(r4 + rr) * CONV_DIM + c4] = o;
    }
}

// ---------------------------------------------------------------------------
// SSD intra-chunk, MFMA. One block per (b, chunk, head), 4 waves.
// Outputs: y_intra (bf16), Schunk (bf16 [n][p]), adec (fp32).
// ---------------------------------------------------------------------------
__global__ __launch_bounds__(256) void ssd_intra_kernel(
    const u16* __restrict__ xc, const float* __restrict__ dtbuf,
    const float* __restrict__ dt_bias, const float* __restrict__ A_log,
    u16* __restrict__ ys, u16* __restrict__ Schunk,
    float* __restrict__ adec, float* __restrict__ ssum)
{
    const int h   = blockIdx.x & 7;
    const int c   = (blockIdx.x >> 3) & 15;
    const int b   = blockIdx.x >> 7;
    const int tid = threadIdx.x;
    const int row0 = b * SEQLEN + c * CHUNK;

    if (tid < 8) ssum[blockIdx.x * 8 + tid] = 0.f;

    __shared__ short Xt[64 * 64];    // [p][t]
    __shared__ short Bn[64 * 64];    // [t][n]
    __shared__ short Cn[64 * 64];    // [t][n]  -> reused as MT [t][tau]
    __shared__ short BTw[64 * 64];   // [n][t], w-folded
    __shared__ float cums[64], dts_s[64], ws_s[64];

    if (tid < 64) {
        const float A = -expf(A_log[h]);
        float raw = dtbuf[(size_t)(row0 + tid) * NHEADS + h] + dt_bias[h];
        float dtv = (raw > 20.f) ? raw : log1pf(expf(raw));
        float v = dtv * A;
        #pragma unroll
        for (int off = 1; off < 64; off <<= 1) {
            float o = __shfl_up(v, off, 64);
            if (tid >= off) v += o;
        }
        float tot = __shfl(v, 63, 64);
        cums[tid]  = v;
        dts_s[tid] = dtv;
        ws_s[tid]  = expf(tot - v) * dtv;
        adec[(size_t)(b * NHEADS + h) * SEQLEN + c * CHUNK + tid] = expf(v);
    }
    __syncthreads();

    {
        const int t2 = (tid >> 3) * 2;
        const int c8 = (tid & 7) * 8;
        const u16* r0 = xc + (size_t)(row0 + t2) * CONV_DIM;
        const u16* r1 = r0 + CONV_DIM;
        u16x8 xv0 = *(const u16x8*)&r0[h * HEADDIM + c8];
        u16x8 xv1 = *(const u16x8*)&r1[h * HEADDIM + c8];
        u16x8 bv0 = *(const u16x8*)&r0[D_INNER + c8];
        u16x8 bv1 = *(const u16x8*)&r1[D_INNER + c8];
        u16x8 cv0 = *(const u16x8*)&r0[D_INNER + D_STATE + c8];
        u16x8 cv1 = *(const u16x8*)&r1[D_INNER + D_STATE + c8];
        *(u16x8*)&Bn[swz(t2,     c8)] = bv0;
        *(u16x8*)&Bn[swz(t2 + 1, c8)] = bv1;
        *(u16x8*)&Cn[swz(t2,     c8)] = cv0;
        *(u16x8*)&Cn[swz(t2 + 1, c8)] = cv1;
        float w0 = ws_s[t2], w1 = ws_s[t2 + 1];
        #pragma unroll
        for (int k = 0; k < 8; k++) {
            wr2u(Xt,  c8 + k, t2, xv0[k], xv1[k]);
            wr2u(BTw, c8 + k, t2, bfc(bf2f(bv0[k]) * w0), bfc(bf2f(bv1[k]) * w1));
        }
    }
    __syncthreads();

    const int lane = tid & 63, w = tid >> 6;
    const int lm = lane & 15, lq = lane >> 4;
    const int tau0 = 16 * w + lq * 4;

    bf16x8 aG0 = ldfrag(Bn, 16 * w + lm, lq);
    bf16x8 aG1 = ldfrag(Bn, 16 * w + lm, 4 + lq);
    f32x4 g[4] = {};
    #pragma unroll
    for (int j = 0; j < 4; j++) {
        g[j] = __builtin_amdgcn_mfma_f32_16x16x32_bf16(aG0, ldfrag(Cn, 16 * j + lm, lq),     g[j], 0, 0, 0);
        g[j] = __builtin_amdgcn_mfma_f32_16x16x32_bf16(aG1, ldfrag(Cn, 16 * j + lm, 4 + lq), g[j], 0, 0, 0);
    }
    float ctau[4], dtau[4];
    *(float4*)&ctau[0] = *(const float4*)&cums[tau0];
    *(float4*)&dtau[0] = *(const float4*)&dts_s[tau0];
    s16x4 mp[4];
    #pragma unroll
    for (int j = 0; j < 4; j++) {
        int t = 16 * j + lm;
        float ct = cums[t];
        #pragma unroll
        for (int r = 0; r < 4; r++) {
            int tau = tau0 + r;
            float m = (t >= tau) ? g[j][r] * __expf(ct - ctau[r]) * dtau[r] : 0.f;
            mp[j][r] = (short)bfc(m);
        }
    }
    __syncthreads();
    #pragma unroll
    for (int j = 0; j < 4; j++)
        *(s16x4*)&Cn[swz(16 * j + lm, tau0)] = mp[j];   // MT[t][tau]
    __syncthreads();

    bf16x8 aY0 = ldfrag(Cn,  16 * w + lm, lq);
    bf16x8 aY1 = ldfrag(Cn,  16 * w + lm, 4 + lq);
    bf16x8 aS0 = ldfrag(BTw, 16 * w + lm, lq);
    bf16x8 aS1 = ldfrag(BTw, 16 * w + lm, 4 + lq);
    f32x4 yv[4] = {}, sv[4] = {};
    #pragma unroll
    for (int j = 0; j < 4; j++) {
        bf16x8 xf0 = ldfrag(Xt, 16 * j + lm, lq);
        bf16x8 xf1 = ldfrag(Xt, 16 * j + lm, 4 + lq);
        yv[j] = __builtin_amdgcn_mfma_f32_16x16x32_bf16(aY0, xf0, yv[j], 0, 0, 0);
        yv[j] = __builtin_amdgcn_mfma_f32_16x16x32_bf16(aY1, xf1, yv[j], 0, 0, 0);
        sv[j] = __builtin_amdgcn_mfma_f32_16x16x32_bf16(aS0, xf0, sv[j], 0, 0, 0);
        sv[j] = __builtin_amdgcn_mfma_f32_16x16x32_bf16(aS1, xf1, sv[j], 0, 0, 0);
    }
    const int mrow = 16 * w + lq * 4;
    #pragma unroll
    for (int j = 0; j < 4; j++)
        #pragma unroll
        for (int r = 0; r < 4; r++)
            ys[(size_t)(row0 + mrow + r) * D_INNER + h * HEADDIM + 16 * j + lm] = bfc(yv[j][r]);
    u16* sb = Schunk + (size_t)((b * NCHUNK + c) * NHEADS + h) * 4096;
    #pragma unroll
    for (int j = 0; j < 4; j++)
        #pragma unroll
        for (int r = 0; r < 4; r++)
            sb[(mrow + r) * 64 + 16 * j + lm] = bfc(sv[j][r]);
}

// ---------------------------------------------------------------------------
// Parallel prefix scan over chunk states. Grid = 64 (b,h) x 4 quarters,
// 256 threads; each thread owns 4 state elements, prefetches all 16 chunk
// values (independent of the recurrence), runs the chain in registers.
// ---------------------------------------------------------------------------
__global__ __launch_bounds__(256) void ssd_state_scan_kernel(
    u16* __restrict__ Schunk, const float* __restrict__ adec)
{
    const int q  = blockIdx.x & 3;
    const int bh = blockIdx.x >> 2;
    const int b  = bh >> 3, h = bh & 7;
    const int base = q * 1024 + threadIdx.x * 4;

    u16x4 v[NCHUNK];
    float atot[NCHUNK];
    #pragma unroll
    for (int c = 0; c < NCHUNK; c++) {
        v[c] = *(const u16x4*)&Schunk[(size_t)((b * NCHUNK + c) * NHEADS + h) * 4096 + base];
        atot[c] = adec[(size_t)bh * SEQLEN + c * CHUNK + 63];
    }
    float run[4] = {0.f, 0.f, 0.f, 0.f};
    #pragma unroll
    for (int c = 0; c < NCHUNK; c++) {
        u16x4 pv;
        #pragma unroll
        for (int k = 0; k < 4; k++) pv[k] = bfc(run[k]);
        *(u16x4*)&Schunk[(size_t)((b * NCHUNK + c) * NHEADS + h) * 4096 + base] = pv;
        #pragma unroll
        for (int k = 0; k < 4; k++)
            run[k] = fmaf(atot[c], run[k], bf2f(v[c][k]));
    }
}

// ---------------------------------------------------------------------------
// Fused inter + gate + RMS partial sum. One block per (b, chunk, half, hpair):
// 32 rows x 2 heads (128 cols). 128 threads (2 waves). ys updated in place
// (v*nw bf16, unnormalized); row sum-of-squares accumulated via atomicAdd.
// ---------------------------------------------------------------------------
__global__ __launch_bounds__(128) void ssd_finish_kernel(
    const u16* __restrict__ xc, const u16* __restrict__ zx,
    const u16* __restrict__ Schunk, const float* __restrict__ adec,
    const float* __restrict__ Dp, const float* __restrict__ nw,
    u16* __restrict__ ys, float* __restrict__ ssum)
{
    const int hp   = blockIdx.x & 3;          // head pair
    const int half = (blockIdx.x >> 2) & 1;
    const int c    = (blockIdx.x >> 3) & 15;
    const int b    = blockIdx.x >> 7;
    const int h0   = hp * 2;
    const int tid  = threadIdx.x;
    const int row0 = b * SEQLEN + c * CHUNK + half * 32;

    __shared__ short Ct[32 * 64];   // [t][n] swizzled
    __shared__ short STs[64 * 64];  // [p][n] swizzled, per-head
    __shared__ float a_s[64];       // [hi][32]
    __shared__ float nw_s[128];

    {   // stage C (32 rows x 64 states), decay rows, norm weights
        int t2 = (tid >> 3) * 2, n8 = (tid & 7) * 8;
        const u16* r0 = xc + (size_t)(row0 + t2) * CONV_DIM + D_INNER + D_STATE;
        u16x8 v0 = *(const u16x8*)&r0[n8];
        u16x8 v1 = *(const u16x8*)&r0[CONV_DIM + n8];
        *(u16x8*)&Ct[swz(t2,     n8)] = v0;
        *(u16x8*)&Ct[swz(t2 + 1, n8)] = v1;
        if (tid < 16) {
            int hh = tid >> 3, t4 = (tid & 7) * 4;
            *(float4*)&a_s[hh * 32 + t4] = *(const float4*)
                &adec[(size_t)(b * NHEADS + h0 + hh) * SEQLEN + c * CHUNK + half * 32 + t4];
        }
        nw_s[tid] = nw[h0 * 64 + tid];
    }

    const int lane = tid & 63, w = tid >> 6;
    const int lm = lane & 15, lq = lane >> 4;
    const int trow = 16 * w + lq * 4;

    bf16x8 aC0, aC1;
    float ss[4] = {0.f, 0.f, 0.f, 0.f};

    for (int hi = 0; hi < 2; hi++) {
        const int h = h0 + hi;
        {   // stage S_h^T: global [n][p] -> LDS [p][n]
            const u16* sb = Schunk + (size_t)((b * NCHUNK + c) * NHEADS + h) * 4096;
            int n4 = (tid >> 3) * 4, p8 = (tid & 7) * 8;
            u16x8 s0 = *(const u16x8*)&sb[(n4 + 0) * 64 + p8];
            u16x8 s1 = *(const u16x8*)&sb[(n4 + 1) * 64 + p8];
            u16x8 s2 = *(const u16x8*)&sb[(n4 + 2) * 64 + p8];
            u16x8 s3 = *(const u16x8*)&sb[(n4 + 3) * 64 + p8];
            #pragma unroll
            for (int k = 0; k < 8; k++) {
                wr2u(STs, p8 + k, n4,     s0[k], s1[k]);
                wr2u(STs, p8 + k, n4 + 2, s2[k], s3[k]);
            }
        }
        __syncthreads();
        if (hi == 0) {
            aC0 = ldfrag(Ct, 16 * w + lm, lq);
            aC1 = ldfrag(Ct, 16 * w + lm, 4 + lq);
        }
        f32x4 U[4] = {};
        #pragma unroll
        for (int j = 0; j < 4; j++) {
            U[j] = __builtin_amdgcn_mfma_f32_16x16x32_bf16(aC0, ldfrag(STs, 16 * j + lm, lq),     U[j], 0, 0, 0);
            U[j] = __builtin_amdgcn_mfma_f32_16x16x32_bf16(aC1, ldfrag(STs, 16 * j + lm, 4 + lq), U[j], 0, 0, 0);
        }
        float Dh = Dp[h];
        #pragma unroll
        for (int j = 0; j < 4; j++) {
            int col = h * 64 + 16 * j + lm;
            float nwv = nw_s[hi * 64 + 16 * j + lm];
            #pragma unroll
            for (int r = 0; r < 4; r++) {
                int row = trow + r;
                size_t grow = (size_t)(row0 + row);
                float a = a_s[hi * 32 + row];
                float u = U[j][r] * a
                        + bf2f(ys[grow * D_INNER + col])
                        + Dh * bf2f(xc[grow * CONV_DIM + col]);
                float zv = bf2f(zx[grow * ZXP + col]);
                float gt = zv / (1.f + expf(-zv));
                float v = u * gt;
                ss[r] = fmaf(v, v, ss[r]);
                ys[grow * D_INNER + col] = bfc(v * nwv);
            }
        }
        __syncthreads();
    }
    #pragma unroll
    for (int r = 0; r < 4; r++) {
        float s = ss[r];
        s += __shfl_xor(s, 1, 64); s += __shfl_xor(s, 2, 64);
        s += __shfl_xor(s, 4, 64); s += __shfl_xor(s, 8, 64);
        if (lm == 0)
            atomicAdd(&ssum[row0 + trow + r], s);
    }
}

// ---------------------------------------------------------------------------
extern "C" void kernel_launch(void* const* d_in, const int* in_sizes, int n_in,
                              void* d_out, int out_size, void* d_ws, size_t ws_size,
                              hipStream_t stream) {
    const float* x          = (const float*)d_in[0];
    const float* in_proj_w  = (const float*)d_in[1];
    const float* conv_w     = (const float*)d_in[2];
    const float* conv_b     = (const float*)d_in[3];
    const float* dt_bias    = (const float*)d_in[4];
    const float* A_log      = (const float*)d_in[5];
    const float* Dp         = (const float*)d_in[6];
    const float* norm_w     = (const float*)d_in[7];
    const float* out_proj_w = (const float*)d_in[8];
    float* out = (float*)d_out;

    u16*   buf_zx = (u16*)d_ws;                                      // 8192 x 1280 bf16
    u16*   buf_xc = buf_zx + (size_t)NROWS * ZXP;                    // 8192 x 640  bf16
    u16*   buf_ys = buf_xc + (size_t)NROWS * CONV_DIM;               // 8192 x 512  bf16
    u16*   buf_S  = buf_ys + (size_t)NROWS * D_INNER;                // 128*8*4096  bf16
    u16*   buf_hb = buf_S  + (size_t)BATCH * NCHUNK * NHEADS * 4096; // 8192 x 256  bf16
    u16*   buf_wi = buf_hb + (size_t)NROWS * D_MODEL;                // 2x1280x256  bf16
    u16*   buf_wo = buf_wi + (size_t)2 * ZXP * D_MODEL;              // 2x256x512   bf16
    float* buf_dt = (float*)(buf_wo + (size_t)2 * D_MODEL * D_INNER);// 8192 x 8    f32
    float* buf_a  = buf_dt + (size_t)NROWS * NHEADS;                 // 64 x 1024   f32
    float* buf_sc = buf_a  + (size_t)BATCH * NHEADS * SEQLEN;        // 8192        f32

    cast_all_kernel<<<(NX_C + NWI_C + NWO_C) / 256, 256, 0, stream>>>(
        x, in_proj_w, out_proj_w, buf_hb, buf_wi, buf_wo);

    for (int i = 0; i < 2; i++) {
        gemm_mfma<__hip_bfloat16, true, false><<<dim3(ZXP / 128, NROWS / 128), 256, 0, stream>>>(
            (const short*)buf_hb, (const short*)(buf_wi + (size_t)i * ZXP * D_MODEL),
            (__hip_bfloat16*)buf_zx, buf_dt, nullptr, ZXP, D_MODEL, D_MODEL);

        conv_silu_kernel<<<(NROWS / 4) * 160 / 256, 256, 0, stream>>>(
            buf_zx, conv_w + (size_t)i * CONV_DIM * D_CONV,
            conv_b + (size_t)i * CONV_DIM, buf_xc);

        ssd_intra_kernel<<<BATCH * NCHUNK * NHEADS, 256, 0, stream>>>(
            buf_xc, buf_dt, dt_bias + i * NHEADS, A_log + i * NHEADS,
            buf_ys, buf_S, buf_a, buf_sc);

        ssd_state_scan_kernel<<<BATCH * NHEADS * 4, 256, 0, stream>>>(buf_S, buf_a);

        ssd_finish_kernel<<<BATCH * NCHUNK * 2 * 4, 128, 0, stream>>>(
            buf_xc, buf_zx, buf_S, buf_a, Dp + i * NHEADS,
            norm_w + (size_t)i * D_INNER, buf_ys, buf_sc);

        if (i == 0) {
            gemm_mfma<__hip_bfloat16, false, true><<<dim3(D_MODEL / 128, NROWS / 128), 256, 0, stream>>>(
                (const short*)buf_ys, (const short*)buf_wo,
                (__hip_bfloat16*)buf_hb, nullptr, buf_sc, D_MODEL, D_INNER, D_INNER);
        } else {
            gemm_mfma<float, false, true><<<dim3(D_MODEL / 128, NROWS / 128), 256, 0, stream>>>(
                (const short*)buf_ys, (const short*)(buf_wo + (size_t)D_MODEL * D_INNER),
                out, nullptr, buf_sc, D_MODEL, D_INNER, D_INNER);
        }
    }
}